// Round 17
// baseline (102.832 us; speedup 1.0000x reference)
//
#include <hip/hip_runtime.h>
#include <math.h>

#define B 4
#define S 4096
#define N 4096
#define BLK 1024           // 16 waves, 1 block/CU (LDS 136 KB)
#define NW 16
#define W 2                // two 32-col B-frags -> 64 s per block
#define JTW 8              // j-tiles (32 rows) per wave = (N/32)/NW
#define INF 3.4e38f

typedef _Float16 f16x8  __attribute__((ext_vector_type(8)));
typedef float    f32x16 __attribute__((ext_vector_type(16)));

// 32x32x16 K-packed Gram MFMA (mapping verified R12-R16), full-N per block,
// SINGLE LDS pass (gfx950 allows 160 KB/workgroup; we use 136 KB).
// A (cloud pt j): {-y0,-y1,-y2, hy_hi, hy_lo, 0,0,0}
// B (grid s, cols=lane&31): lanes<32 {x0,x1,x2,1,1,0,0,0}; lanes>=32 zero
// (kills A's k=8..15 garbage). D[j][s] = hy - x.y ; u = hx + min_j D.
__global__ __launch_bounds__(BLK) void sdf_mfma(
    const float* __restrict__ grid,   // [B,S,3]
    const float* __restrict__ gts,    // [B,N,3]
    const float* __restrict__ preds,  // [B,N,3]
    float* __restrict__ pb)           // [B][S/64] block sums
{
    __shared__ float4 Ap[N];          // 64 KB
    __shared__ float4 Ag[N];          // 64 KB
    __shared__ float  sm[NW * 2 * 64]; // 8 KB (separate -> no reuse barrier)

    const int tid   = threadIdx.x;
    const int lane  = tid & 63;
    const int wv    = tid >> 6;       // 0..15
    const int l31   = lane & 31;
    const int stile = blockIdx.x;     // 64 tiles of 64 s
    const int b     = blockIdx.y;
    const int scol  = stile * 64;

    // ---- B-frags + hx ----
    const bool lo32 = (lane < 32);
    f16x8 bf[W];
    float hx[W];
    #pragma unroll
    for (int w = 0; w < W; ++w) {
        const float* xp = grid + ((size_t)b * S + scol + w * 32 + l31) * 3;
        float x0 = (float)(_Float16)xp[0];
        float x1 = (float)(_Float16)xp[1];
        float x2 = (float)(_Float16)xp[2];
        hx[w] = 0.5f * (x0 * x0 + x1 * x1 + x2 * x2);
        f16x8 bb = { (_Float16)x0, (_Float16)x1, (_Float16)x2,
                     (_Float16)1.f, (_Float16)1.f,
                     (_Float16)0.f, (_Float16)0.f, (_Float16)0.f };
        f16x8 z  = { (_Float16)0.f, (_Float16)0.f, (_Float16)0.f, (_Float16)0.f,
                     (_Float16)0.f, (_Float16)0.f, (_Float16)0.f, (_Float16)0.f };
        bf[w] = lo32 ? bb : z;
    }

    // ---- stage + pack ALL of N in one pass ----
    // waves 0-7 stage preds, 8-15 stage gts; thread handles 8 pts = 6 float4.
    {
        const bool doP = (tid < BLK / 2);
        const int  st  = tid & (BLK / 2 - 1);          // 0..511
        const float4* csrc =
            (const float4*)((doP ? preds : gts) + (size_t)b * N * 3);
        float4* Abuf = doP ? Ap : Ag;
        const int fo = 6 * st;                          // float4 offset
        const float4 r0 = csrc[fo + 0], r1 = csrc[fo + 1], r2 = csrc[fo + 2];
        const float4 r3 = csrc[fo + 3], r4 = csrc[fo + 4], r5 = csrc[fo + 5];
        const float ys[8][3] = {
            { r0.x, r0.y, r0.z }, { r0.w, r1.x, r1.y },
            { r1.z, r1.w, r2.x }, { r2.y, r2.z, r2.w },
            { r3.x, r3.y, r3.z }, { r3.w, r4.x, r4.y },
            { r4.z, r4.w, r5.x }, { r5.y, r5.z, r5.w } };
        #pragma unroll
        for (int k = 0; k < 8; ++k) {
            float y0 = (float)(_Float16)ys[k][0];
            float y1 = (float)(_Float16)ys[k][1];
            float y2 = (float)(_Float16)ys[k][2];
            float hy = 0.5f * (y0 * y0 + y1 * y1 + y2 * y2);
            _Float16 hh = (_Float16)hy;
            _Float16 hl = (_Float16)(hy - (float)hh);
            f16x8 a = { (_Float16)(-y0), (_Float16)(-y1), (_Float16)(-y2),
                        hh, hl, (_Float16)0.f, (_Float16)0.f, (_Float16)0.f };
            *(f16x8*)&Abuf[8 * st + k] = a;
        }
    }
    __syncthreads();

    const f32x16 zc = { 0.f, 0.f, 0.f, 0.f, 0.f, 0.f, 0.f, 0.f,
                        0.f, 0.f, 0.f, 0.f, 0.f, 0.f, 0.f, 0.f };
    // split accumulators: two independent min chains per cloud per w
    float accpa[W], accpb[W], accga[W], accgb[W];
    #pragma unroll
    for (int w = 0; w < W; ++w) {
        accpa[w] = INF; accpb[w] = INF; accga[w] = INF; accgb[w] = INF;
    }

    // ---- compute: wave's JTW j-tiles of 32 rows ----
    const char* app = (const char*)Ap + ((size_t)wv * JTW * 32 + l31) * 16;
    const char* agp = (const char*)Ag + ((size_t)wv * JTW * 32 + l31) * 16;
    #pragma unroll
    for (int jt = 0; jt < JTW; ++jt) {
        const f16x8 afp = *(const f16x8*)(app + jt * 512);
        const f16x8 afg = *(const f16x8*)(agp + jt * 512);
        #pragma unroll
        for (int w = 0; w < W; ++w) {
            f32x16 d = __builtin_amdgcn_mfma_f32_32x32x16_f16(afp, bf[w], zc, 0, 0, 0);
            float a0 = accpa[w], a1 = accpb[w];
            a0 = fminf(fminf(a0, d[0]),  d[1]);    // chain A: d[0..7]
            a0 = fminf(fminf(a0, d[2]),  d[3]);
            a0 = fminf(fminf(a0, d[4]),  d[5]);
            a0 = fminf(fminf(a0, d[6]),  d[7]);
            a1 = fminf(fminf(a1, d[8]),  d[9]);    // chain B: d[8..15]
            a1 = fminf(fminf(a1, d[10]), d[11]);
            a1 = fminf(fminf(a1, d[12]), d[13]);
            a1 = fminf(fminf(a1, d[14]), d[15]);
            accpa[w] = a0; accpb[w] = a1;
        }
        #pragma unroll
        for (int w = 0; w < W; ++w) {
            f32x16 d = __builtin_amdgcn_mfma_f32_32x32x16_f16(afg, bf[w], zc, 0, 0, 0);
            float a0 = accga[w], a1 = accgb[w];
            a0 = fminf(fminf(a0, d[0]),  d[1]);
            a0 = fminf(fminf(a0, d[2]),  d[3]);
            a0 = fminf(fminf(a0, d[4]),  d[5]);
            a0 = fminf(fminf(a0, d[6]),  d[7]);
            a1 = fminf(fminf(a1, d[8]),  d[9]);
            a1 = fminf(fminf(a1, d[10]), d[11]);
            a1 = fminf(fminf(a1, d[12]), d[13]);
            a1 = fminf(fminf(a1, d[14]), d[15]);
            accga[w] = a0; accgb[w] = a1;
        }
    }

    // ---- cross-lane + cross-wave fold (sm separate: no extra barrier) ----
    #pragma unroll
    for (int w = 0; w < W; ++w) {
        const float ap = fminf(accpa[w], accpb[w]);
        const float ag = fminf(accga[w], accgb[w]);
        float mp = fminf(ap, __shfl_xor(ap, 32, 64));
        float mg = fminf(ag, __shfl_xor(ag, 32, 64));
        if (lo32) {
            sm[(wv * 2 + 0) * 64 + w * 32 + l31] = hx[w] + mp;
            sm[(wv * 2 + 1) * 64 + w * 32 + l31] = hx[w] + mg;
        }
    }
    __syncthreads();
    if (tid < 64) {
        float mp = INF, mg = INF;
        #pragma unroll
        for (int v = 0; v < NW; ++v) {
            mp = fminf(mp, sm[(v * 2 + 0) * 64 + tid]);
            mg = fminf(mg, sm[(v * 2 + 1) * 64 + tid]);
        }
        float v = fabsf(sqrtf(fmaxf(2.f * mp, 0.f)) - sqrtf(fmaxf(2.f * mg, 0.f)));
        v += __shfl_down(v, 32, 64);
        v += __shfl_down(v, 16, 64);
        v += __shfl_down(v, 8, 64);
        v += __shfl_down(v, 4, 64);
        v += __shfl_down(v, 2, 64);
        v += __shfl_down(v, 1, 64);
        if (tid == 0) pb[b * 64 + stile] = v;
    }
}

// Final: 256 threads = 4 waves; wave b reduces its 64 tile-sums -> out[b].
__global__ __launch_bounds__(256) void sdf_final(
    const float* __restrict__ pb, float* __restrict__ out)
{
    const int tid = threadIdx.x;
    float v = pb[tid];
    #pragma unroll
    for (int off = 32; off > 0; off >>= 1)
        v += __shfl_down(v, off, 64);
    if ((tid & 63) == 0) out[tid >> 6] = v / (float)S;
}

extern "C" void kernel_launch(void* const* d_in, const int* in_sizes, int n_in,
                              void* d_out, int out_size, void* d_ws, size_t ws_size,
                              hipStream_t stream) {
    const float* grid  = (const float*)d_in[0];
    const float* gts   = (const float*)d_in[1];
    const float* preds = (const float*)d_in[2];
    float* out = (float*)d_out;
    float* pb  = (float*)d_ws;        // 256 floats

    dim3 g1(S / 64, B);               // (64, 4) = 256 blocks, 1/CU
    sdf_mfma<<<g1, BLK, 0, stream>>>(grid, gts, preds, pb);

    sdf_final<<<1, 256, 0, stream>>>(pb, out);
}

// Round 18
// 13.290 us; speedup vs baseline: 7.7374x; 7.7374x over previous
//
#include <hip/hip_runtime.h>
#include <math.h>

#define B 4
#define S 4096
#define N 4096
#define BLK 1024           // 16 waves, 1 block/CU, 4 waves/SIMD
#define NW 16
#define W 2                // two 32-col B-frags -> 64 s per block
#define PASS 2048          // cloud pts per LDS pass per cloud (32 KB x 2 clouds)
#define NPASS 2
#define JTW 4              // j-tiles (32 rows) per wave per pass = PASS/32/NW
#define INF 3.4e38f

typedef _Float16 f16x8  __attribute__((ext_vector_type(8)));
typedef float    f32x16 __attribute__((ext_vector_type(16)));

// 32x32x16 K-packed Gram MFMA, full-N per block (R12 body, verified).
// A (cloud pt j): {-y0,-y1,-y2, hy_hi, hy_lo, 0,0,0}
// B (grid s, cols=lane&31): lanes<32 {x0,x1,x2,1,1,0,0,0}; lanes>=32 zero
// (kills A's k=8..15 garbage). D[j][s] = hy - x.y ; u = hx + min_j D.
// KEY CHANGE vs R12: __launch_bounds__(1024, 4) -> VGPR cap 128 (not the
// compiler-default 64 that spilled in R17), plus split fold chains.
__global__ __launch_bounds__(BLK, 4) void sdf_mfma(
    const float* __restrict__ grid,   // [B,S,3]
    const float* __restrict__ gts,    // [B,N,3]
    const float* __restrict__ preds,  // [B,N,3]
    float* __restrict__ pb)           // [B][S/64]
{
    __shared__ float4 Ap[PASS];       // 32 KB
    __shared__ float4 Ag[PASS];       // 32 KB

    const int tid   = threadIdx.x;
    const int lane  = tid & 63;
    const int wv    = tid >> 6;       // 0..15
    const int l31   = lane & 31;
    const int stile = blockIdx.x;     // 64 tiles of 64 s
    const int b     = blockIdx.y;
    const int scol  = stile * 64;

    // ---- B-frags + hx (cols = lane&31; lanes 32-63 zero kill k=8..15) ----
    const bool lo32 = (lane < 32);
    f16x8 bf[W];
    float hx[W];
    #pragma unroll
    for (int w = 0; w < W; ++w) {
        const float* xp = grid + ((size_t)b * S + scol + w * 32 + l31) * 3;
        float x0 = (float)(_Float16)xp[0];
        float x1 = (float)(_Float16)xp[1];
        float x2 = (float)(_Float16)xp[2];
        hx[w] = 0.5f * (x0 * x0 + x1 * x1 + x2 * x2);
        f16x8 bb = { (_Float16)x0, (_Float16)x1, (_Float16)x2,
                     (_Float16)1.f, (_Float16)1.f,
                     (_Float16)0.f, (_Float16)0.f, (_Float16)0.f };
        f16x8 z  = { (_Float16)0.f, (_Float16)0.f, (_Float16)0.f, (_Float16)0.f,
                     (_Float16)0.f, (_Float16)0.f, (_Float16)0.f, (_Float16)0.f };
        bf[w] = lo32 ? bb : z;
    }

    float accpa[W], accpb[W], accga[W], accgb[W];
    #pragma unroll
    for (int w = 0; w < W; ++w) {
        accpa[w] = INF; accpb[w] = INF; accga[w] = INF; accgb[w] = INF;
    }

    const f32x16 zc = { 0.f, 0.f, 0.f, 0.f, 0.f, 0.f, 0.f, 0.f,
                        0.f, 0.f, 0.f, 0.f, 0.f, 0.f, 0.f, 0.f };

    for (int p = 0; p < NPASS; ++p) {
        if (p) __syncthreads();            // prior pass fully consumed
        // ---- stage + pack pass p (2 frags per cloud per thread, as R12) ----
        #pragma unroll
        for (int q = 0; q < PASS / BLK; ++q) {
            const int n = p * PASS + q * BLK + tid;
            const int d = q * BLK + tid;
            const float* yp = preds + ((size_t)b * N + n) * 3;
            float y0 = (float)(_Float16)yp[0];
            float y1 = (float)(_Float16)yp[1];
            float y2 = (float)(_Float16)yp[2];
            float hy = 0.5f * (y0 * y0 + y1 * y1 + y2 * y2);
            _Float16 hh = (_Float16)hy;
            _Float16 hl = (_Float16)(hy - (float)hh);
            f16x8 a = { (_Float16)(-y0), (_Float16)(-y1), (_Float16)(-y2),
                        hh, hl, (_Float16)0.f, (_Float16)0.f, (_Float16)0.f };
            *(f16x8*)&Ap[d] = a;

            const float* gp = gts + ((size_t)b * N + n) * 3;
            y0 = (float)(_Float16)gp[0];
            y1 = (float)(_Float16)gp[1];
            y2 = (float)(_Float16)gp[2];
            hy = 0.5f * (y0 * y0 + y1 * y1 + y2 * y2);
            hh = (_Float16)hy;
            hl = (_Float16)(hy - (float)hh);
            f16x8 g = { (_Float16)(-y0), (_Float16)(-y1), (_Float16)(-y2),
                        hh, hl, (_Float16)0.f, (_Float16)0.f, (_Float16)0.f };
            *(f16x8*)&Ag[d] = g;
        }
        __syncthreads();

        // ---- compute: wave's JTW j-tiles of 32 rows ----
        const char* app = (const char*)Ap + ((size_t)wv * JTW * 32 + l31) * 16;
        const char* agp = (const char*)Ag + ((size_t)wv * JTW * 32 + l31) * 16;
        #pragma unroll
        for (int jt = 0; jt < JTW; ++jt) {
            const f16x8 afp = *(const f16x8*)(app + jt * 512);
            const f16x8 afg = *(const f16x8*)(agp + jt * 512);
            #pragma unroll
            for (int w = 0; w < W; ++w) {
                f32x16 d = __builtin_amdgcn_mfma_f32_32x32x16_f16(afp, bf[w], zc, 0, 0, 0);
                float a0 = accpa[w], a1 = accpb[w];
                a0 = fminf(fminf(a0, d[0]),  d[1]);    // chain A: d[0..7]
                a0 = fminf(fminf(a0, d[2]),  d[3]);
                a0 = fminf(fminf(a0, d[4]),  d[5]);
                a0 = fminf(fminf(a0, d[6]),  d[7]);
                a1 = fminf(fminf(a1, d[8]),  d[9]);    // chain B: d[8..15]
                a1 = fminf(fminf(a1, d[10]), d[11]);
                a1 = fminf(fminf(a1, d[12]), d[13]);
                a1 = fminf(fminf(a1, d[14]), d[15]);
                accpa[w] = a0; accpb[w] = a1;
            }
            #pragma unroll
            for (int w = 0; w < W; ++w) {
                f32x16 d = __builtin_amdgcn_mfma_f32_32x32x16_f16(afg, bf[w], zc, 0, 0, 0);
                float a0 = accga[w], a1 = accgb[w];
                a0 = fminf(fminf(a0, d[0]),  d[1]);
                a0 = fminf(fminf(a0, d[2]),  d[3]);
                a0 = fminf(fminf(a0, d[4]),  d[5]);
                a0 = fminf(fminf(a0, d[6]),  d[7]);
                a1 = fminf(fminf(a1, d[8]),  d[9]);
                a1 = fminf(fminf(a1, d[10]), d[11]);
                a1 = fminf(fminf(a1, d[12]), d[13]);
                a1 = fminf(fminf(a1, d[14]), d[15]);
                accga[w] = a0; accgb[w] = a1;
            }
        }
        __syncthreads();   // buffer consumed before re-stage / sm reuse
    }

    // ---- cross-lane + cross-wave fold + block tail (as R12) ----
    float* sm = (float*)Ap;   // reuse LDS: [NW][2][64] (barrier above)
    #pragma unroll
    for (int w = 0; w < W; ++w) {
        const float ap = fminf(accpa[w], accpb[w]);
        const float ag = fminf(accga[w], accgb[w]);
        float mp = fminf(ap, __shfl_xor(ap, 32, 64));
        float mg = fminf(ag, __shfl_xor(ag, 32, 64));
        if (lo32) {
            sm[(wv * 2 + 0) * 64 + w * 32 + l31] = hx[w] + mp;
            sm[(wv * 2 + 1) * 64 + w * 32 + l31] = hx[w] + mg;
        }
    }
    __syncthreads();
    if (tid < 64) {
        float mp = INF, mg = INF;
        #pragma unroll
        for (int v = 0; v < NW; ++v) {
            mp = fminf(mp, sm[(v * 2 + 0) * 64 + tid]);
            mg = fminf(mg, sm[(v * 2 + 1) * 64 + tid]);
        }
        float v = fabsf(sqrtf(fmaxf(2.f * mp, 0.f)) - sqrtf(fmaxf(2.f * mg, 0.f)));
        #pragma unroll
        for (int off = 32; off > 0; off >>= 1)
            v += __shfl_down(v, off, 64);
        if (tid == 0) pb[b * 64 + stile] = v;
    }
}

// Final: 256 threads = 4 waves; wave b reduces its 64 tile-sums -> out[b].
__global__ __launch_bounds__(256) void sdf_final(
    const float* __restrict__ pb, float* __restrict__ out)
{
    const int tid = threadIdx.x;
    float v = pb[tid];
    #pragma unroll
    for (int off = 32; off > 0; off >>= 1)
        v += __shfl_down(v, off, 64);
    if ((tid & 63) == 0) out[tid >> 6] = v / (float)S;
}

extern "C" void kernel_launch(void* const* d_in, const int* in_sizes, int n_in,
                              void* d_out, int out_size, void* d_ws, size_t ws_size,
                              hipStream_t stream) {
    const float* grid  = (const float*)d_in[0];
    const float* gts   = (const float*)d_in[1];
    const float* preds = (const float*)d_in[2];
    float* out = (float*)d_out;
    float* pb  = (float*)d_ws;        // 256 floats

    dim3 g1(S / 64, B);               // (64, 4) = 256 blocks, 1/CU
    sdf_mfma<<<g1, BLK, 0, stream>>>(grid, gts, preds, pb);

    sdf_final<<<1, 256, 0, stream>>>(pb, out);
}

// Round 19
// 13.259 us; speedup vs baseline: 7.7555x; 1.0023x over previous
//
#include <hip/hip_runtime.h>
#include <math.h>

#define B 4
#define S 4096
#define N 4096
#define BLK 1024           // 16 waves, 1 block/CU, 4 waves/SIMD
#define NW 16
#define W 2                // two 32-col B-frags -> 64 s per block
#define JTW 8              // j-tiles (32 rows) per wave = (N/32)/NW
#define INF 3.4e38f

typedef _Float16 f16x8  __attribute__((ext_vector_type(8)));
typedef float    f32x16 __attribute__((ext_vector_type(16)));

// 32x32x16 K-packed Gram MFMA (mapping verified R12-R18), full-N per block,
// NO LDS STAGING: waves partition the j-range (each cloud point consumed by
// exactly one wave), so each lane loads its own row directly from global
// (3 dword loads; hi lanes duplicate lo -> L1 broadcast; their A-values are
// don't-care because B zeroes k=8..15). Zero barriers until the final 8 KB
// cross-wave fold.
// A (cloud pt j): {-y0,-y1,-y2, hy_hi, hy_lo, 0,0,0}
// B (grid s, cols=lane&31): lanes<32 {x0,x1,x2,1,1,0,0,0}; lanes>=32 zero.
// D[j][s] = hy - x.y ; u = hx + min_j D ; d = sqrt(max(2u,0)).
__global__ __launch_bounds__(BLK, 4) void sdf_mfma(
    const float* __restrict__ grid,   // [B,S,3]
    const float* __restrict__ gts,    // [B,N,3]
    const float* __restrict__ preds,  // [B,N,3]
    float* __restrict__ pb)           // [B][S/64]
{
    __shared__ float sm[NW * 2 * 64]; // 8 KB only

    const int tid   = threadIdx.x;
    const int lane  = tid & 63;
    const int wv    = tid >> 6;       // 0..15
    const int l31   = lane & 31;
    const int stile = blockIdx.x;     // 64 tiles of 64 s
    const int b     = blockIdx.y;
    const int scol  = stile * 64;

    // ---- B-frags + hx (cols = lane&31; lanes 32-63 zero kill k=8..15) ----
    const bool lo32 = (lane < 32);
    f16x8 bf[W];
    float hx[W];
    #pragma unroll
    for (int w = 0; w < W; ++w) {
        const float* xp = grid + ((size_t)b * S + scol + w * 32 + l31) * 3;
        float x0 = (float)(_Float16)xp[0];
        float x1 = (float)(_Float16)xp[1];
        float x2 = (float)(_Float16)xp[2];
        hx[w] = 0.5f * (x0 * x0 + x1 * x1 + x2 * x2);
        f16x8 bb = { (_Float16)x0, (_Float16)x1, (_Float16)x2,
                     (_Float16)1.f, (_Float16)1.f,
                     (_Float16)0.f, (_Float16)0.f, (_Float16)0.f };
        f16x8 z  = { (_Float16)0.f, (_Float16)0.f, (_Float16)0.f, (_Float16)0.f,
                     (_Float16)0.f, (_Float16)0.f, (_Float16)0.f, (_Float16)0.f };
        bf[w] = lo32 ? bb : z;
    }

    // per-lane row base within the wave's j-slice: rows jt0 + l31
    const size_t cb = (size_t)b * N * 3;
    const float* pp = preds + cb + ((size_t)(wv * JTW * 32) + l31) * 3;
    const float* gg = gts   + cb + ((size_t)(wv * JTW * 32) + l31) * 3;

    const f32x16 zc = { 0.f, 0.f, 0.f, 0.f, 0.f, 0.f, 0.f, 0.f,
                        0.f, 0.f, 0.f, 0.f, 0.f, 0.f, 0.f, 0.f };
    float accpa = INF, accpb = INF, accga = INF, accgb = INF;

    #pragma unroll
    for (int jt = 0; jt < JTW; ++jt) {
        // ---- preds: load own row, pack, 2 MFMAs, fold ----
        {
            const float* yp = pp + (size_t)jt * 32 * 3;
            float y0 = (float)(_Float16)yp[0];
            float y1 = (float)(_Float16)yp[1];
            float y2 = (float)(_Float16)yp[2];
            float hy = 0.5f * (y0 * y0 + y1 * y1 + y2 * y2);
            _Float16 hh = (_Float16)hy;
            _Float16 hl = (_Float16)(hy - (float)hh);
            const f16x8 af = { (_Float16)(-y0), (_Float16)(-y1), (_Float16)(-y2),
                               hh, hl, (_Float16)0.f, (_Float16)0.f, (_Float16)0.f };
            #pragma unroll
            for (int w = 0; w < W; ++w) {
                f32x16 d = __builtin_amdgcn_mfma_f32_32x32x16_f16(af, bf[w], zc, 0, 0, 0);
                float a0 = (w == 0) ? accpa : accpb;   // chain per w
                a0 = fminf(fminf(a0, d[0]),  d[1]);
                a0 = fminf(fminf(a0, d[2]),  d[3]);
                a0 = fminf(fminf(a0, d[4]),  d[5]);
                a0 = fminf(fminf(a0, d[6]),  d[7]);
                a0 = fminf(fminf(a0, d[8]),  d[9]);
                a0 = fminf(fminf(a0, d[10]), d[11]);
                a0 = fminf(fminf(a0, d[12]), d[13]);
                a0 = fminf(fminf(a0, d[14]), d[15]);
                if (w == 0) accpa = a0; else accpb = a0;
            }
        }
        // ---- gts ----
        {
            const float* yp = gg + (size_t)jt * 32 * 3;
            float y0 = (float)(_Float16)yp[0];
            float y1 = (float)(_Float16)yp[1];
            float y2 = (float)(_Float16)yp[2];
            float hy = 0.5f * (y0 * y0 + y1 * y1 + y2 * y2);
            _Float16 hh = (_Float16)hy;
            _Float16 hl = (_Float16)(hy - (float)hh);
            const f16x8 af = { (_Float16)(-y0), (_Float16)(-y1), (_Float16)(-y2),
                               hh, hl, (_Float16)0.f, (_Float16)0.f, (_Float16)0.f };
            #pragma unroll
            for (int w = 0; w < W; ++w) {
                f32x16 d = __builtin_amdgcn_mfma_f32_32x32x16_f16(af, bf[w], zc, 0, 0, 0);
                float a0 = (w == 0) ? accga : accgb;
                a0 = fminf(fminf(a0, d[0]),  d[1]);
                a0 = fminf(fminf(a0, d[2]),  d[3]);
                a0 = fminf(fminf(a0, d[4]),  d[5]);
                a0 = fminf(fminf(a0, d[6]),  d[7]);
                a0 = fminf(fminf(a0, d[8]),  d[9]);
                a0 = fminf(fminf(a0, d[10]), d[11]);
                a0 = fminf(fminf(a0, d[12]), d[13]);
                a0 = fminf(fminf(a0, d[14]), d[15]);
                if (w == 0) accga = a0; else accgb = a0;
            }
        }
    }

    // ---- cross-lane (row halves) + cross-wave fold + block tail ----
    // NOTE: accpa/accpb are w=0 / w=1 (NOT mergeable); per-w cross-lane fold.
    {
        float mp0 = fminf(accpa, __shfl_xor(accpa, 32, 64));
        float mp1 = fminf(accpb, __shfl_xor(accpb, 32, 64));
        float mg0 = fminf(accga, __shfl_xor(accga, 32, 64));
        float mg1 = fminf(accgb, __shfl_xor(accgb, 32, 64));
        if (lo32) {
            sm[(wv * 2 + 0) * 64 +  0 + l31] = hx[0] + mp0;
            sm[(wv * 2 + 0) * 64 + 32 + l31] = hx[1] + mp1;
            sm[(wv * 2 + 1) * 64 +  0 + l31] = hx[0] + mg0;
            sm[(wv * 2 + 1) * 64 + 32 + l31] = hx[1] + mg1;
        }
    }
    __syncthreads();
    if (tid < 64) {
        float mp = INF, mg = INF;
        #pragma unroll
        for (int v = 0; v < NW; ++v) {
            mp = fminf(mp, sm[(v * 2 + 0) * 64 + tid]);
            mg = fminf(mg, sm[(v * 2 + 1) * 64 + tid]);
        }
        float v = fabsf(sqrtf(fmaxf(2.f * mp, 0.f)) - sqrtf(fmaxf(2.f * mg, 0.f)));
        v += __shfl_down(v, 32, 64);
        v += __shfl_down(v, 16, 64);
        v += __shfl_down(v, 8, 64);
        v += __shfl_down(v, 4, 64);
        v += __shfl_down(v, 2, 64);
        v += __shfl_down(v, 1, 64);
        if (tid == 0) pb[b * 64 + stile] = v;
    }
}

// Final: 256 threads = 4 waves; wave b reduces its 64 tile-sums -> out[b].
__global__ __launch_bounds__(256) void sdf_final(
    const float* __restrict__ pb, float* __restrict__ out)
{
    const int tid = threadIdx.x;
    float v = pb[tid];
    #pragma unroll
    for (int off = 32; off > 0; off >>= 1)
        v += __shfl_down(v, off, 64);
    if ((tid & 63) == 0) out[tid >> 6] = v / (float)S;
}

extern "C" void kernel_launch(void* const* d_in, const int* in_sizes, int n_in,
                              void* d_out, int out_size, void* d_ws, size_t ws_size,
                              hipStream_t stream) {
    const float* grid  = (const float*)d_in[0];
    const float* gts   = (const float*)d_in[1];
    const float* preds = (const float*)d_in[2];
    float* out = (float*)d_out;
    float* pb  = (float*)d_ws;        // 256 floats

    dim3 g1(S / 64, B);               // (64, 4) = 256 blocks, 1/CU
    sdf_mfma<<<g1, BLK, 0, stream>>>(grid, gts, preds, pb);

    sdf_final<<<1, 256, 0, stream>>>(pb, out);
}